// Round 1
// 33286.920 us; speedup vs baseline: 1.6376x; 1.6376x over previous
//
#include <hip/hip_runtime.h>

#define VOCAB  30
#define HID    512
#define KS     128
#define VS     128
#define EMB    256
#define TT     1000
#define NB     256
#define MAXLEN 250

// ---------------- old-path layout (kept as fallback) ----------------
#define NH (NB*HID)          // 131072
#define NK (NB*KS)           // 32768
#define OFF_CTX (6*NH + 3*NK)
#define WS_TOTAL (OFF_CTX + NK)
#define STATE_BYTES ((size_t)WS_TOTAL * 4)     // 3,670,016
#define VBF_BYTES   ((size_t)TT * NB * VS * 2) // 65,536,000

// ---------------- new-path (MFMA split-bf16) layout ----------------
#define K1 (EMB + VS + HID)     // 896
#define K2 (HID + HID)          // 1024
#define K3 (HID + KS)           // 640
#define W1SZ (4*HID*K1)         // 1,835,008
#define W2SZ (4*HID*K2)         // 2,097,152
#define W3SZ (4*KS*K3)          //   327,680
#define EMBSZ (VOCAB*EMB)       //     7,680
#define BS1 (4*HID)
#define BS2 (4*HID)
#define BS3 (4*KS)

constexpr size_t NEW_BASE  = STATE_BYTES + VBF_BYTES;          // 69,206,016 (256B aligned)
constexpr size_t OFF_W1HI  = NEW_BASE;
constexpr size_t OFF_W1LO  = OFF_W1HI + (size_t)W1SZ*2;
constexpr size_t OFF_W2HI  = OFF_W1LO + (size_t)W1SZ*2;
constexpr size_t OFF_W2LO  = OFF_W2HI + (size_t)W2SZ*2;
constexpr size_t OFF_W3HI  = OFF_W2LO + (size_t)W2SZ*2;
constexpr size_t OFF_W3LO  = OFF_W3HI + (size_t)W3SZ*2;
constexpr size_t OFF_EMBHI = OFF_W3LO + (size_t)W3SZ*2;
constexpr size_t OFF_EMBLO = OFF_EMBHI + (size_t)EMBSZ*2;
constexpr size_t OFF_BSUM  = OFF_EMBLO + (size_t)EMBSZ*2;
constexpr size_t OFF_CTXHI = OFF_BSUM  + (size_t)(BS1+BS2+BS3)*4;
constexpr size_t OFF_CTXLO = OFF_CTXHI + (size_t)NB*VS*2;
constexpr size_t OFF_H1HI  = OFF_CTXLO + (size_t)NB*VS*2;   // zero-init region starts here
constexpr size_t OFF_H1LO  = OFF_H1HI + (size_t)2*NH*2;
constexpr size_t OFF_H2HI  = OFF_H1LO + (size_t)2*NH*2;
constexpr size_t OFF_H2LO  = OFF_H2HI + (size_t)2*NH*2;
constexpr size_t OFF_H3HI  = OFF_H2LO + (size_t)2*NH*2;
constexpr size_t OFF_H3LO  = OFF_H3HI + (size_t)2*NK*2;
constexpr size_t OFF_H3F   = OFF_H3LO + (size_t)2*NK*2;
constexpr size_t OFF_C1    = OFF_H3F  + (size_t)NK*4;
constexpr size_t OFF_C2    = OFF_C1 + (size_t)NH*4;
constexpr size_t OFF_C3    = OFF_C2 + (size_t)NH*4;
constexpr size_t FULL_BYTES= OFF_C3 + (size_t)NK*4;         // ~90.1 MB
constexpr size_t ZERO_BASE = OFF_H1HI;
constexpr size_t ZERO_BYTES= FULL_BYTES - OFF_H1HI;         // 3,670,016

typedef __attribute__((ext_vector_type(8))) short bf16x8;
typedef __attribute__((ext_vector_type(4))) float f32x4;
typedef unsigned short u16;

__device__ __forceinline__ float sigmoidf_(float x){ return 1.0f/(1.0f+__expf(-x)); }

__device__ __forceinline__ u16 f2bf_(float x){
    unsigned int u = __float_as_uint(x);
    return (u16)((u + 0x7fffu + ((u >> 16) & 1u)) >> 16);  // RNE
}
__device__ __forceinline__ float bf2f_(u16 h){ return __uint_as_float((unsigned)h << 16); }

// ================= prep kernels (new path, once per launch) =================

__global__ __launch_bounds__(256)
void pack_w_kernel(const float* __restrict__ wih, const float* __restrict__ whh,
                   u16* __restrict__ hi, u16* __restrict__ lo, int KIN, int KH, int total)
{
    int i = blockIdx.x*256 + threadIdx.x;
    if (i >= total) return;
    const int KW = KIN + KH;
    int g = i / KW, k = i - g*KW;
    float v = (k < KIN) ? wih[g*KIN + k] : whh[g*KH + (k - KIN)];
    u16 h = f2bf_(v);
    hi[i] = h;
    lo[i] = f2bf_(v - bf2f_(h));
}

__global__ __launch_bounds__(256)
void prep_misc_kernel(char* __restrict__ wsb, const float* __restrict__ embW,
                      const float* __restrict__ bi1, const float* __restrict__ bh1,
                      const float* __restrict__ bi2, const float* __restrict__ bh2,
                      const float* __restrict__ bi3, const float* __restrict__ bh3,
                      const float* __restrict__ values)
{
    const int gt = blockIdx.x*256 + threadIdx.x;
    const int gs = gridDim.x*256;
    u16* Ehi = (u16*)(wsb + OFF_EMBHI);
    u16* Elo = (u16*)(wsb + OFF_EMBLO);
    for (int i = gt; i < EMBSZ; i += gs){
        float v = embW[i]; u16 h = f2bf_(v);
        Ehi[i]=h; Elo[i]=f2bf_(v - bf2f_(h));
    }
    float* bs = (float*)(wsb + OFF_BSUM);
    for (int i = gt; i < BS1; i += gs) bs[i]         = bi1[i]+bh1[i];
    for (int i = gt; i < BS2; i += gs) bs[BS1+i]     = bi2[i]+bh2[i];
    for (int i = gt; i < BS3; i += gs) bs[BS1+BS2+i] = bi3[i]+bh3[i];
    u16* Chi = (u16*)(wsb + OFF_CTXHI);
    u16* Clo = (u16*)(wsb + OFF_CTXLO);
    const float* v0 = values + (size_t)(TT-1)*NB*VS;
    for (int i = gt; i < NB*VS; i += gs){
        float v = v0[i]; u16 h = f2bf_(v);
        Chi[i]=h; Clo[i]=f2bf_(v - bf2f_(h));
    }
    uint4* z = (uint4*)(wsb + ZERO_BASE);
    uint4 zz; zz.x=0; zz.y=0; zz.z=0; zz.w=0;
    for (size_t i = (size_t)gt; i < ZERO_BYTES/16; i += (size_t)gs) z[i] = zz;
}

// ================= MFMA split-bf16 LSTM =================
// G[g][n] = sum_k W[g][k]*X[n][k], g = q*H + h (q=gate i,f,g,o).
// MFMA 16x16x32 bf16, A = X fragment (row=lane&15 -> n, k=8*(lane>>4)+j),
// B = W^T fragment (col=lane&15 -> g, same k), D: row=(lane>>4)*4+r -> n, col=lane&15 -> h.
// Per wave: 16 n x (16 h x 4 gates); split-bf16 -> 3 MFMA per (frag,kstep).

__device__ __forceinline__ void lstm_step(const u16* const wh[4], const u16* const wl[4], int kw,
                                          bf16x8 ah, bf16x8 al, f32x4 acc[4])
{
    #pragma unroll
    for (int q=0;q<4;q++){
        bf16x8 wH = *(const bf16x8*)(wh[q] + kw);
        bf16x8 wL = *(const bf16x8*)(wl[q] + kw);
        acc[q] = __builtin_amdgcn_mfma_f32_16x16x32_bf16(ah, wH, acc[q], 0,0,0);
        acc[q] = __builtin_amdgcn_mfma_f32_16x16x32_bf16(al, wH, acc[q], 0,0,0);
        acc[q] = __builtin_amdgcn_mfma_f32_16x16x32_bf16(ah, wL, acc[q], 0,0,0);
    }
}

template<int H, int KIN, int KH, int MODE>
__global__ __launch_bounds__(128)
void lstm_mfma(const u16* __restrict__ Whi, const u16* __restrict__ Wlo,
               const float* __restrict__ bsum,
               const u16* __restrict__ xhi, const u16* __restrict__ xlo,   // MODE0: ctx[N][VS]; MODE1: [N][KIN]
               const u16* __restrict__ ehi, const u16* __restrict__ elo,   // MODE0 only: embW split
               const int* __restrict__ text, int step,
               const u16* __restrict__ hphi, const u16* __restrict__ hplo, // [N][KH]
               u16* __restrict__ hohi, u16* __restrict__ holo,             // [N][H]
               float* __restrict__ hof,                                    // nullable fp32 h out
               float* __restrict__ cbuf)                                   // [N][H]
{
    constexpr int KW = KIN + KH;
    constexpr int HT = H/16;
    const int lane = threadIdx.x & 63;
    const int gw   = blockIdx.x*2 + (threadIdx.x >> 6);   // 2 waves/block
    const int ht   = gw % HT, nt = gw / HT;
    const int l15  = lane & 15, lhi = lane >> 4;
    const int n    = nt*16 + l15;
    const int koff = lhi*8;
    const int h0   = ht*16;

    const u16* wh[4]; const u16* wl[4];
    #pragma unroll
    for (int q=0;q<4;q++){
        size_t off = (size_t)(q*H + h0 + l15)*KW + koff;
        wh[q] = Whi + off; wl[q] = Wlo + off;
    }

    f32x4 acc[4];
    f32x4 zr = {0.f,0.f,0.f,0.f};
    #pragma unroll
    for (int q=0;q<4;q++) acc[q] = zr;

    int kb;
    if constexpr (MODE == 0) {
        const int trow = text[n*MAXLEN + step];
        const u16* Eh = ehi + trow*EMB + koff;
        const u16* El = elo + trow*EMB + koff;
        #pragma unroll 4
        for (int s=0;s<EMB/32;s++)
            lstm_step(wh, wl, s*32, *(const bf16x8*)(Eh + s*32), *(const bf16x8*)(El + s*32), acc);
        const u16* Ch = xhi + n*VS + koff;
        const u16* Cl = xlo + n*VS + koff;
        #pragma unroll
        for (int s=0;s<VS/32;s++)
            lstm_step(wh, wl, EMB + s*32, *(const bf16x8*)(Ch + s*32), *(const bf16x8*)(Cl + s*32), acc);
        kb = EMB + VS;
    } else {
        const u16* Xh = xhi + n*KIN + koff;
        const u16* Xl = xlo + n*KIN + koff;
        #pragma unroll 4
        for (int s=0;s<KIN/32;s++)
            lstm_step(wh, wl, s*32, *(const bf16x8*)(Xh + s*32), *(const bf16x8*)(Xl + s*32), acc);
        kb = KIN;
    }
    {
        const u16* Hh = hphi + n*KH + koff;
        const u16* Hl = hplo + n*KH + koff;
        #pragma unroll 4
        for (int s=0;s<KH/32;s++)
            lstm_step(wh, wl, kb + s*32, *(const bf16x8*)(Hh + s*32), *(const bf16x8*)(Hl + s*32), acc);
    }

    // fused cell update: lane holds gates (i,f,g,o) for n = nt*16+lhi*4+r, h = h0+l15
    const int hcol = h0 + l15;
    const float b0 = bsum[0*H + hcol], b1 = bsum[1*H + hcol];
    const float b2 = bsum[2*H + hcol], b3 = bsum[3*H + hcol];
    const int nr0 = nt*16 + lhi*4;
    #pragma unroll
    for (int r=0;r<4;r++){
        const size_t p = (size_t)(nr0 + r)*H + hcol;
        const float gi = acc[0][r] + b0;
        const float gf = acc[1][r] + b1;
        const float gg = acc[2][r] + b2;
        const float go = acc[3][r] + b3;
        const float cn = sigmoidf_(gf)*cbuf[p] + sigmoidf_(gi)*tanhf(gg);
        const float hn = sigmoidf_(go)*tanhf(cn);
        cbuf[p] = cn;
        const u16 hb = f2bf_(hn);
        hohi[p] = hb;
        holo[p] = f2bf_(hn - bf2f_(hb));
        if (hof) hof[p] = hn;
    }
}

// ================= old fallback kernels (unchanged logic) =================

__global__ __launch_bounds__(256)
void init_kernel(float* __restrict__ ws, const float* __restrict__ values){
    int i = blockIdx.x*256 + threadIdx.x;
    if (i >= WS_TOTAL) return;
    if (i < OFF_CTX) ws[i] = 0.0f;
    else ws[i] = values[(size_t)(TT-1)*NB*VS + (i - OFF_CTX)];
}

__global__ __launch_bounds__(256)
void conv_bf16_kernel(const float* __restrict__ src, u16* __restrict__ dst, int n4){
    int i = blockIdx.x*256 + threadIdx.x;
    if (i >= n4) return;
    float4 v = ((const float4*)src)[i];
    ushort4 o;
    o.x = f2bf_(v.x); o.y = f2bf_(v.y); o.z = f2bf_(v.z); o.w = f2bf_(v.w);
    ((ushort4*)dst)[i] = o;
}

template<int H, int KX, int KH, int MODE>
__global__ __launch_bounds__(256)
void lstm_kernel(const float* __restrict__ Wx, const float* __restrict__ Wh,
                 const float* __restrict__ bx, const float* __restrict__ bh,
                 const float* __restrict__ xbuf, const float* __restrict__ embW,
                 const int* __restrict__ text, int step,
                 const float* __restrict__ hread, float* __restrict__ hwrite,
                 float* __restrict__ cbuf)
{
    __shared__ __align__(16) float Xs[16][68];
    __shared__ __align__(16) float Ws[16][68];
    __shared__ float Gs[64][65];

    const int tid = threadIdx.x;
    const int h0  = blockIdx.x * 16;
    const int n0  = blockIdx.y * 64;

    const int sr = tid >> 2;
    const int sk = (tid & 3) << 2;
    const int wrow = (sr >> 4) * H + h0 + (sr & 15);
    const int n  = n0 + sr;

    const int tn4 = (tid & 15) * 4;
    const int tc4 = (tid >> 4) * 4;

    float acc[4][4];
    #pragma unroll
    for (int i=0;i<4;i++){
        #pragma unroll
        for (int j=0;j<4;j++) acc[i][j]=0.0f;
    }

    for (int k0 = 0; k0 < KX + KH; k0 += 16) {
        const int kb = k0 + sk;
        float4 xv, wv;
        if (k0 < KX) {
            if constexpr (MODE == 0) {
                if (kb < EMB) {
                    int idx = text[n * MAXLEN + step];
                    xv = *(const float4*)(embW + idx*EMB + kb);
                } else {
                    xv = *(const float4*)(xbuf + n*VS + (kb - EMB));
                }
            } else {
                xv = *(const float4*)(xbuf + n*KX + kb);
            }
            wv = *(const float4*)(Wx + wrow*KX + kb);
        } else {
            const int kh = kb - KX;
            xv = *(const float4*)(hread + n*KH + kh);
            wv = *(const float4*)(Wh + wrow*KH + kh);
        }
        Xs[sk+0][sr]=xv.x; Xs[sk+1][sr]=xv.y; Xs[sk+2][sr]=xv.z; Xs[sk+3][sr]=xv.w;
        Ws[sk+0][sr]=wv.x; Ws[sk+1][sr]=wv.y; Ws[sk+2][sr]=wv.z; Ws[sk+3][sr]=wv.w;
        __syncthreads();
        #pragma unroll
        for (int kk=0;kk<16;kk++){
            float4 xr = *(const float4*)&Xs[kk][tn4];
            float4 wr = *(const float4*)&Ws[kk][tc4];
            acc[0][0] += wr.x*xr.x; acc[0][1] += wr.x*xr.y; acc[0][2] += wr.x*xr.z; acc[0][3] += wr.x*xr.w;
            acc[1][0] += wr.y*xr.x; acc[1][1] += wr.y*xr.y; acc[1][2] += wr.y*xr.z; acc[1][3] += wr.y*xr.w;
            acc[2][0] += wr.z*xr.x; acc[2][1] += wr.z*xr.y; acc[2][2] += wr.z*xr.z; acc[2][3] += wr.z*xr.w;
            acc[3][0] += wr.w*xr.x; acc[3][1] += wr.w*xr.y; acc[3][2] += wr.w*xr.z; acc[3][3] += wr.w*xr.w;
        }
        __syncthreads();
    }

    #pragma unroll
    for (int ci=0; ci<4; ci++){
        const int c = tc4 + ci;
        const int row = (c >> 4) * H + h0 + (c & 15);
        const float b = bx[row] + bh[row];
        #pragma unroll
        for (int ni=0; ni<4; ni++) Gs[c][tn4+ni] = acc[ci][ni] + b;
    }
    __syncthreads();

    for (int p = tid; p < 16*64; p += 256){
        const int hl = p & 15, nl = p >> 4;
        const float gi = Gs[     hl][nl];
        const float gf = Gs[16 + hl][nl];
        const float gg = Gs[32 + hl][nl];
        const float go = Gs[48 + hl][nl];
        const int gn = n0 + nl, gh = h0 + hl;
        const float cold = cbuf[gn*H + gh];
        const float cn = sigmoidf_(gf)*cold + sigmoidf_(gi)*tanhf(gg);
        const float hn = sigmoidf_(go)*tanhf(cn);
        cbuf[gn*H + gh] = cn;
        hwrite[gn*H + gh] = hn;
    }
}

// ================= attention + prediction (shared) =================
// BF: values are bf16; CSPLIT: write ctx as bf16 hi/lo (new path) vs fp32 (old path).
template<int BF, int CSPLIT>
__global__ __launch_bounds__(512)
void attn_pred_kernel(const float* __restrict__ keys, const void* __restrict__ values_v,
                      const int* __restrict__ seqlen, const float* __restrict__ h3,
                      const float* __restrict__ linW, const float* __restrict__ linb,
                      const float* __restrict__ charW, const float* __restrict__ charb,
                      float* __restrict__ ctx, u16* __restrict__ ctx_hi, u16* __restrict__ ctx_lo,
                      float* __restrict__ out, int step)
{
    __shared__ float es[TT];
    __shared__ float redm[8], reds[8];
    __shared__ float cpart[8][128];
    __shared__ float cat[256];
    __shared__ float mid[128];

    const int tid  = threadIdx.x;
    const int n    = blockIdx.x;
    const int wave = tid >> 6, lane = tid & 63;

    const float2 hv = *(const float2*)(h3 + n*KS + lane*2);
    const int L = seqlen[n];

    for (int t0 = wave*4; t0 < TT; t0 += 32) {
        const float2* kp = (const float2*)(keys + ((size_t)t0*NB + n)*KS) + lane;
        const size_t rs = (size_t)NB*KS/2;
        float2 k0 = kp[0], k1 = kp[rs], k2 = kp[2*rs], k3 = kp[3*rs];
        float d0 = k0.x*hv.x + k0.y*hv.y;
        float d1 = k1.x*hv.x + k1.y*hv.y;
        float d2 = k2.x*hv.x + k2.y*hv.y;
        float d3 = k3.x*hv.x + k3.y*hv.y;
        #pragma unroll
        for (int off=32; off; off>>=1){
            d0 += __shfl_xor(d0, off, 64);
            d1 += __shfl_xor(d1, off, 64);
            d2 += __shfl_xor(d2, off, 64);
            d3 += __shfl_xor(d3, off, 64);
        }
        if (lane == 0){
            es[t0+0] = (t0+0 < L) ? d0 : -1e9f;
            es[t0+1] = (t0+1 < L) ? d1 : -1e9f;
            es[t0+2] = (t0+2 < L) ? d2 : -1e9f;
            es[t0+3] = (t0+3 < L) ? d3 : -1e9f;
        }
    }
    __syncthreads();

    float m = -3e38f;
    for (int t = tid; t < TT; t += 512) m = fmaxf(m, es[t]);
    #pragma unroll
    for (int off=32; off; off>>=1) m = fmaxf(m, __shfl_xor(m, off, 64));
    if (lane == 0) redm[wave] = m;
    __syncthreads();
    m = redm[0];
    #pragma unroll
    for (int w=1; w<8; ++w) m = fmaxf(m, redm[w]);

    float s = 0.0f;
    for (int t = tid; t < TT; t += 512) { float p = __expf(es[t]-m); es[t] = p; s += p; }
    #pragma unroll
    for (int off=32; off; off>>=1) s += __shfl_xor(s, off, 64);
    if (lane == 0) reds[wave] = s;
    __syncthreads();
    s = reds[0];
    #pragma unroll
    for (int w=1; w<8; ++w) s += reds[w];
    const float inv = 1.0f / s;

    float* attn_out = out + (size_t)NB*MAXLEN*VOCAB + ((size_t)step*NB + n)*TT;
    for (int t = tid; t < TT; t += 512) { float a = es[t]*inv; es[t] = a; attn_out[t] = a; }
    __syncthreads();

    float cax = 0.0f, cay = 0.0f;
    if constexpr (BF) {
        const u16* vals = (const u16*)values_v;
        #pragma unroll 4
        for (int j = 0; j < 125; ++j){
            const int t = wave + 8*j;
            const float a = es[t];
            const unsigned int v2 = *((const unsigned int*)(vals + ((size_t)t*NB + n)*VS) + lane);
            cax += a * __uint_as_float(v2 << 16);
            cay += a * __uint_as_float(v2 & 0xffff0000u);
        }
    } else {
        const float* vals = (const float*)values_v;
        #pragma unroll 4
        for (int j = 0; j < 125; ++j){
            const int t = wave + 8*j;
            const float a = es[t];
            const float2 v2 = *((const float2*)(vals + ((size_t)t*NB + n)*VS) + lane);
            cax += a * v2.x;
            cay += a * v2.y;
        }
    }
    cpart[wave][lane*2]   = cax;
    cpart[wave][lane*2+1] = cay;
    __syncthreads();

    if (tid < 128) {
        float cv = 0.0f;
        #pragma unroll
        for (int w=0; w<8; ++w) cv += cpart[w][tid];
        if constexpr (CSPLIT) {
            const u16 hb = f2bf_(cv);
            ctx_hi[n*VS + tid] = hb;
            ctx_lo[n*VS + tid] = f2bf_(cv - bf2f_(hb));
        } else {
            ctx[n*VS + tid] = cv;
        }
        cat[tid]        = h3[n*KS + tid];
        cat[128 + tid]  = cv;
    }
    __syncthreads();

    if (tid < 256) {
        const int o  = tid >> 1;
        const int kh = (tid & 1) * 128;
        const float* w = linW + o*(KS+VS) + kh;
        float a = 0.0f;
        #pragma unroll 8
        for (int k=0; k<128; ++k) a += w[k]*cat[kh+k];
        a += __shfl_xor(a, 1, 64);
        if (!(tid & 1)) mid[o] = a + linb[o];
    }
    __syncthreads();

    if (tid < VOCAB) {
        float a = charb[tid];
        const float* w = charW + tid*KS;
        #pragma unroll 8
        for (int k=0; k<KS; ++k) a += w[k]*mid[k];
        out[((size_t)n*MAXLEN + step)*VOCAB + tid] = a;
    }
}

// ================= host =================

extern "C" void kernel_launch(void* const* d_in, const int* in_sizes, int n_in,
                              void* d_out, int out_size, void* d_ws, size_t ws_size,
                              hipStream_t stream)
{
    const float* keys   = (const float*)d_in[0];
    const float* values = (const float*)d_in[1];
    const int*   seqlen = (const int*)  d_in[2];
    const int*   text   = (const int*)  d_in[3];
    const float* embW   = (const float*)d_in[4];
    const float* w_ih1  = (const float*)d_in[5];
    const float* w_hh1  = (const float*)d_in[6];
    const float* b_ih1  = (const float*)d_in[7];
    const float* b_hh1  = (const float*)d_in[8];
    const float* w_ih2  = (const float*)d_in[9];
    const float* w_hh2  = (const float*)d_in[10];
    const float* b_ih2  = (const float*)d_in[11];
    const float* b_hh2  = (const float*)d_in[12];
    const float* w_ih3  = (const float*)d_in[13];
    const float* w_hh3  = (const float*)d_in[14];
    const float* b_ih3  = (const float*)d_in[15];
    const float* b_hh3  = (const float*)d_in[16];
    const float* linW   = (const float*)d_in[17];
    const float* linb   = (const float*)d_in[18];
    const float* charW  = (const float*)d_in[19];
    const float* charb  = (const float*)d_in[20];
    float* out = (float*)d_out;
    float* ws  = (float*)d_ws;
    char*  wsb = (char*)d_ws;

    u16* vals_bf = (u16*)(wsb + STATE_BYTES);
    const int n4 = TT*NB*VS/4;

    if (ws_size >= FULL_BYTES) {
        // ---------- new MFMA split-bf16 path ----------
        u16* W1hi=(u16*)(wsb+OFF_W1HI); u16* W1lo=(u16*)(wsb+OFF_W1LO);
        u16* W2hi=(u16*)(wsb+OFF_W2HI); u16* W2lo=(u16*)(wsb+OFF_W2LO);
        u16* W3hi=(u16*)(wsb+OFF_W3HI); u16* W3lo=(u16*)(wsb+OFF_W3LO);
        u16* Ehi =(u16*)(wsb+OFF_EMBHI); u16* Elo =(u16*)(wsb+OFF_EMBLO);
        float* bs=(float*)(wsb+OFF_BSUM);
        u16* Chi =(u16*)(wsb+OFF_CTXHI); u16* Clo =(u16*)(wsb+OFF_CTXLO);
        u16* H1hi=(u16*)(wsb+OFF_H1HI);  u16* H1lo=(u16*)(wsb+OFF_H1LO);
        u16* H2hi=(u16*)(wsb+OFF_H2HI);  u16* H2lo=(u16*)(wsb+OFF_H2LO);
        u16* H3hi=(u16*)(wsb+OFF_H3HI);  u16* H3lo=(u16*)(wsb+OFF_H3LO);
        float* H3f=(float*)(wsb+OFF_H3F);
        float* C1=(float*)(wsb+OFF_C1);
        float* C2=(float*)(wsb+OFF_C2);
        float* C3=(float*)(wsb+OFF_C3);

        pack_w_kernel<<<(W1SZ+255)/256, 256, 0, stream>>>(w_ih1, w_hh1, W1hi, W1lo, EMB+VS, HID, W1SZ);
        pack_w_kernel<<<(W2SZ+255)/256, 256, 0, stream>>>(w_ih2, w_hh2, W2hi, W2lo, HID,    HID, W2SZ);
        pack_w_kernel<<<(W3SZ+255)/256, 256, 0, stream>>>(w_ih3, w_hh3, W3hi, W3lo, HID,    KS,  W3SZ);
        conv_bf16_kernel<<<(n4 + 255)/256, 256, 0, stream>>>(values, vals_bf, n4);
        prep_misc_kernel<<<1024, 256, 0, stream>>>(wsb, embW, b_ih1,b_hh1, b_ih2,b_hh2, b_ih3,b_hh3, values);

        constexpr int G12 = (HID/16)*(NB/16)/2;  // 256 blocks, 2 waves each
        constexpr int G3  = (KS/16)*(NB/16)/2;   // 64 blocks

        for (int t = 0; t < MAXLEN; ++t) {
            const int cur = t & 1, nxt = cur ^ 1;
            lstm_mfma<HID, EMB+VS, HID, 0><<<G12, 128, 0, stream>>>(
                W1hi, W1lo, bs, Chi, Clo, Ehi, Elo, text, t,
                H1hi + cur*NH, H1lo + cur*NH,
                H1hi + nxt*NH, H1lo + nxt*NH, nullptr, C1);
            lstm_mfma<HID, HID, HID, 1><<<G12, 128, 0, stream>>>(
                W2hi, W2lo, bs + BS1, H1hi + nxt*NH, H1lo + nxt*NH, nullptr, nullptr, nullptr, 0,
                H2hi + cur*NH, H2lo + cur*NH,
                H2hi + nxt*NH, H2lo + nxt*NH, nullptr, C2);
            lstm_mfma<KS, HID, KS, 1><<<G3, 128, 0, stream>>>(
                W3hi, W3lo, bs + BS1 + BS2, H2hi + nxt*NH, H2lo + nxt*NH, nullptr, nullptr, nullptr, 0,
                H3hi + cur*NK, H3lo + cur*NK,
                H3hi + nxt*NK, H3lo + nxt*NK, H3f, C3);
            attn_pred_kernel<1,1><<<NB, 512, 0, stream>>>(
                keys, vals_bf, seqlen, H3f, linW, linb, charW, charb,
                nullptr, Chi, Clo, out, t);
        }
        return;
    }

    // ---------- old fallback path ----------
    float* h1  = ws;
    float* c1  = h1 + 2*NH;
    float* h2  = c1 + NH;
    float* c2  = h2 + 2*NH;
    float* h3  = c2 + NH;
    float* c3  = h3 + 2*NK;
    float* ctx = c3 + NK;

    const bool use_bf16 = (ws_size >= STATE_BYTES + VBF_BYTES);

    init_kernel<<<(WS_TOTAL + 255)/256, 256, 0, stream>>>(ws, values);
    if (use_bf16) {
        conv_bf16_kernel<<<(n4 + 255)/256, 256, 0, stream>>>(values, vals_bf, n4);
    }

    for (int t = 0; t < MAXLEN; ++t) {
        const int cur = t & 1, nxt = cur ^ 1;
        lstm_kernel<HID, EMB+VS, HID, 0><<<dim3(HID/16, NB/64), 256, 0, stream>>>(
            w_ih1, w_hh1, b_ih1, b_hh1, ctx, embW, text, t,
            h1 + cur*NH, h1 + nxt*NH, c1);
        lstm_kernel<HID, HID, HID, 1><<<dim3(HID/16, NB/64), 256, 0, stream>>>(
            w_ih2, w_hh2, b_ih2, b_hh2, h1 + nxt*NH, nullptr, nullptr, t,
            h2 + cur*NH, h2 + nxt*NH, c2);
        lstm_kernel<KS, HID, KS, 1><<<dim3(KS/16, NB/64), 256, 0, stream>>>(
            w_ih3, w_hh3, b_ih3, b_hh3, h2 + nxt*NH, nullptr, nullptr, t,
            h3 + cur*NK, h3 + nxt*NK, c3);
        if (use_bf16)
            attn_pred_kernel<1,0><<<NB, 512, 0, stream>>>(
                keys, vals_bf, seqlen, h3 + nxt*NK,
                linW, linb, charW, charb, ctx, nullptr, nullptr, out, t);
        else
            attn_pred_kernel<0,0><<<NB, 512, 0, stream>>>(
                keys, values, seqlen, h3 + nxt*NK,
                linW, linb, charW, charb, ctx, nullptr, nullptr, out, t);
    }
}

// Round 2
// 27763.831 us; speedup vs baseline: 1.9633x; 1.1989x over previous
//
#include <hip/hip_runtime.h>

#define VOCAB  30
#define HID    512
#define KS     128
#define VS     128
#define EMB    256
#define TT     1000
#define NB     256
#define MAXLEN 250

// ---------------- old-path layout (kept as fallback) ----------------
#define NH (NB*HID)          // 131072
#define NK (NB*KS)           // 32768
#define OFF_CTX (6*NH + 3*NK)
#define WS_TOTAL (OFF_CTX + NK)
#define STATE_BYTES ((size_t)WS_TOTAL * 4)     // 3,670,016
#define VBF_BYTES   ((size_t)TT * NB * VS * 2) // 65,536,000

// ---------------- new-path (MFMA split-bf16) layout ----------------
#define K1 (EMB + VS + HID)     // 896
#define K2 (HID + HID)          // 1024
#define K3 (HID + KS)           // 640
#define W1SZ (4*HID*K1)         // 1,835,008
#define W2SZ (4*HID*K2)         // 2,097,152
#define W3SZ (4*KS*K3)          //   327,680
#define EMBSZ (VOCAB*EMB)       //     7,680
#define BS1 (4*HID)
#define BS2 (4*HID)
#define BS3 (4*KS)

constexpr size_t NEW_BASE  = STATE_BYTES + VBF_BYTES;          // 69,206,016 (256B aligned)
constexpr size_t OFF_W1HI  = NEW_BASE;
constexpr size_t OFF_W1LO  = OFF_W1HI + (size_t)W1SZ*2;
constexpr size_t OFF_W2HI  = OFF_W1LO + (size_t)W1SZ*2;
constexpr size_t OFF_W2LO  = OFF_W2HI + (size_t)W2SZ*2;
constexpr size_t OFF_W3HI  = OFF_W2LO + (size_t)W2SZ*2;
constexpr size_t OFF_W3LO  = OFF_W3HI + (size_t)W3SZ*2;
constexpr size_t OFF_EMBHI = OFF_W3LO + (size_t)W3SZ*2;
constexpr size_t OFF_EMBLO = OFF_EMBHI + (size_t)EMBSZ*2;
constexpr size_t OFF_BSUM  = OFF_EMBLO + (size_t)EMBSZ*2;
constexpr size_t OFF_CTXHI = OFF_BSUM  + (size_t)(BS1+BS2+BS3)*4;
constexpr size_t OFF_CTXLO = OFF_CTXHI + (size_t)NB*VS*2;
constexpr size_t OFF_H1HI  = OFF_CTXLO + (size_t)NB*VS*2;   // zero-init region starts here
constexpr size_t OFF_H1LO  = OFF_H1HI + (size_t)2*NH*2;
constexpr size_t OFF_H2HI  = OFF_H1LO + (size_t)2*NH*2;
constexpr size_t OFF_H2LO  = OFF_H2HI + (size_t)2*NH*2;
constexpr size_t OFF_H3HI  = OFF_H2LO + (size_t)2*NH*2;
constexpr size_t OFF_H3LO  = OFF_H3HI + (size_t)2*NK*2;
constexpr size_t OFF_H3F   = OFF_H3LO + (size_t)2*NK*2;
constexpr size_t OFF_C1    = OFF_H3F  + (size_t)NK*4;
constexpr size_t OFF_C2    = OFF_C1 + (size_t)NH*4;
constexpr size_t OFF_C3    = OFF_C2 + (size_t)NH*4;
constexpr size_t FULL_BYTES= OFF_C3 + (size_t)NK*4;         // ~90.1 MB
constexpr size_t ZERO_BASE = OFF_H1HI;
constexpr size_t ZERO_BYTES= FULL_BYTES - OFF_H1HI;         // 3,670,016

typedef __attribute__((ext_vector_type(8))) short bf16x8;
typedef __attribute__((ext_vector_type(4))) float f32x4;
typedef unsigned short u16;

__device__ __forceinline__ float sigmoidf_(float x){ return 1.0f/(1.0f+__expf(-x)); }

__device__ __forceinline__ u16 f2bf_(float x){
    unsigned int u = __float_as_uint(x);
    return (u16)((u + 0x7fffu + ((u >> 16) & 1u)) >> 16);  // RNE
}
__device__ __forceinline__ float bf2f_(u16 h){ return __uint_as_float((unsigned)h << 16); }

// ================= prep kernels (new path, once per launch) =================

__global__ __launch_bounds__(256)
void pack_w_kernel(const float* __restrict__ wih, const float* __restrict__ whh,
                   u16* __restrict__ hi, u16* __restrict__ lo, int KIN, int KH, int total)
{
    int i = blockIdx.x*256 + threadIdx.x;
    if (i >= total) return;
    const int KW = KIN + KH;
    int g = i / KW, k = i - g*KW;
    float v = (k < KIN) ? wih[g*KIN + k] : whh[g*KH + (k - KIN)];
    u16 h = f2bf_(v);
    hi[i] = h;
    lo[i] = f2bf_(v - bf2f_(h));
}

__global__ __launch_bounds__(256)
void prep_misc_kernel(char* __restrict__ wsb, const float* __restrict__ embW,
                      const float* __restrict__ bi1, const float* __restrict__ bh1,
                      const float* __restrict__ bi2, const float* __restrict__ bh2,
                      const float* __restrict__ bi3, const float* __restrict__ bh3,
                      const float* __restrict__ values)
{
    const int gt = blockIdx.x*256 + threadIdx.x;
    const int gs = gridDim.x*256;
    u16* Ehi = (u16*)(wsb + OFF_EMBHI);
    u16* Elo = (u16*)(wsb + OFF_EMBLO);
    for (int i = gt; i < EMBSZ; i += gs){
        float v = embW[i]; u16 h = f2bf_(v);
        Ehi[i]=h; Elo[i]=f2bf_(v - bf2f_(h));
    }
    float* bs = (float*)(wsb + OFF_BSUM);
    for (int i = gt; i < BS1; i += gs) bs[i]         = bi1[i]+bh1[i];
    for (int i = gt; i < BS2; i += gs) bs[BS1+i]     = bi2[i]+bh2[i];
    for (int i = gt; i < BS3; i += gs) bs[BS1+BS2+i] = bi3[i]+bh3[i];
    u16* Chi = (u16*)(wsb + OFF_CTXHI);
    u16* Clo = (u16*)(wsb + OFF_CTXLO);
    const float* v0 = values + (size_t)(TT-1)*NB*VS;
    for (int i = gt; i < NB*VS; i += gs){
        float v = v0[i]; u16 h = f2bf_(v);
        Chi[i]=h; Clo[i]=f2bf_(v - bf2f_(h));
    }
    uint4* z = (uint4*)(wsb + ZERO_BASE);
    uint4 zz; zz.x=0; zz.y=0; zz.z=0; zz.w=0;
    for (size_t i = (size_t)gt; i < ZERO_BYTES/16; i += (size_t)gs) z[i] = zz;
}

// ================= MFMA split-bf16 LSTM (4-way split-K) =================
// G[g][n] = sum_k W[g][k]*X[n][k], g = q*H + h (q=gate i,f,g,o).
// MFMA 16x16x32 bf16, A = X fragment (row=lane&15 -> n, k=8*(lane>>4)+j),
// B = W^T fragment (col=lane&15 -> g, same k), D: row=(lane>>4)*4+r -> n, col=lane&15 -> h.
// One block (4 waves) per 16x16 output tile; wave w computes K-slice w,
// partials reduced via LDS, wave 0 does the fused cell update.
// Block->tile mapping is XCD-aware: bid%8 selects XCD (round-robin dispatch),
// so each XCD reads only HT/8 weight column-tiles -> weights L2-resident per XCD.

__device__ __forceinline__ void lstm_step(const u16* const wh[4], const u16* const wl[4], int kw,
                                          bf16x8 ah, bf16x8 al, f32x4 acc[4])
{
    #pragma unroll
    for (int q=0;q<4;q++){
        bf16x8 wH = *(const bf16x8*)(wh[q] + kw);
        bf16x8 wL = *(const bf16x8*)(wl[q] + kw);
        acc[q] = __builtin_amdgcn_mfma_f32_16x16x32_bf16(ah, wH, acc[q], 0,0,0);
        acc[q] = __builtin_amdgcn_mfma_f32_16x16x32_bf16(al, wH, acc[q], 0,0,0);
        acc[q] = __builtin_amdgcn_mfma_f32_16x16x32_bf16(ah, wL, acc[q], 0,0,0);
    }
}

template<int H, int KIN, int KH, int MODE>
__global__ __launch_bounds__(256)
void lstm_mfma4(const u16* __restrict__ Whi, const u16* __restrict__ Wlo,
                const float* __restrict__ bsum,
                const u16* __restrict__ xhi, const u16* __restrict__ xlo,   // MODE0: ctx[N][VS]; MODE1: [N][KIN]
                const u16* __restrict__ ehi, const u16* __restrict__ elo,   // MODE0 only: embW split
                const int* __restrict__ text, int step,
                const u16* __restrict__ hphi, const u16* __restrict__ hplo, // [N][KH]
                u16* __restrict__ hohi, u16* __restrict__ holo,             // [N][H]
                float* __restrict__ hof,                                    // nullable fp32 h out
                float* __restrict__ cbuf)                                   // [N][H]
{
    constexpr int KW  = KIN + KH;
    constexpr int HT  = H/16;
    constexpr int NT  = NB/16;
    constexpr int S32 = KW/32;     // 28 / 32 / 20
    constexpr int SPW = S32/4;     //  7 /  8 /  5
    static_assert(SPW*4 == S32, "K must split 4 ways");
    static_assert((HT & 7) == 0 || HT == 8, "HT divisible by 8");

    __shared__ float red[3][4][4][64];   // 12 KB

    const int tid  = threadIdx.x;
    const int lane = tid & 63;
    const int wave = tid >> 6;

    const int bid = blockIdx.x;
    const int x = bid & 7, j = bid >> 3;
    const int ht = x*(HT/8) + j/NT;
    const int nt = j % NT;

    const int l15  = lane & 15, lhi = lane >> 4;
    const int n    = nt*16 + l15;
    const int koff = lhi*8;
    const int h0   = ht*16;

    const u16* wh[4]; const u16* wl[4];
    #pragma unroll
    for (int q=0;q<4;q++){
        size_t off = (size_t)(q*H + h0 + l15)*KW + koff;
        wh[q] = Whi + off; wl[q] = Wlo + off;
    }

    f32x4 acc[4];
    f32x4 zr = {0.f,0.f,0.f,0.f};
    #pragma unroll
    for (int q=0;q<4;q++) acc[q] = zr;

    // activation base pointers (per lane)
    const u16 *b0h, *b0l;
    if constexpr (MODE==0){
        const int trow = text[n*MAXLEN + step];
        b0h = ehi + trow*EMB + koff; b0l = elo + trow*EMB + koff;
    } else {
        b0h = xhi + n*KIN + koff;    b0l = xlo + n*KIN + koff;
    }
    const u16* bch = (MODE==0) ? (xhi + n*VS + koff) : nullptr;  // ctx
    const u16* bcl = (MODE==0) ? (xlo + n*VS + koff) : nullptr;
    const u16* bhh = hphi + n*KH + koff;
    const u16* bhl = hplo + n*KH + koff;

    #pragma unroll
    for (int si=0; si<SPW; ++si){
        const int s = wave*SPW + si;
        const int k = s*32;
        const u16 *ph, *pl;
        if constexpr (MODE==0){
            if (k < EMB)          { ph = b0h + k;           pl = b0l + k; }
            else if (k < EMB+VS)  { ph = bch + (k-EMB);     pl = bcl + (k-EMB); }
            else                  { ph = bhh + (k-EMB-VS);  pl = bhl + (k-EMB-VS); }
        } else {
            if (k < KIN)          { ph = b0h + k;           pl = b0l + k; }
            else                  { ph = bhh + (k-KIN);     pl = bhl + (k-KIN); }
        }
        lstm_step(wh, wl, k, *(const bf16x8*)ph, *(const bf16x8*)pl, acc);
    }

    if (wave >= 1){
        #pragma unroll
        for (int q=0;q<4;q++)
            #pragma unroll
            for (int r=0;r<4;r++)
                red[wave-1][q][r][lane] = acc[q][r];
    }
    __syncthreads();

    if (wave == 0){
        #pragma unroll
        for (int q=0;q<4;q++)
            #pragma unroll
            for (int r=0;r<4;r++)
                acc[q][r] += red[0][q][r][lane] + red[1][q][r][lane] + red[2][q][r][lane];

        // fused cell update: lane holds gates for n = nt*16+lhi*4+r, h = h0+l15
        const int hcol = h0 + l15;
        const float bb0 = bsum[0*H + hcol], bb1 = bsum[1*H + hcol];
        const float bb2 = bsum[2*H + hcol], bb3 = bsum[3*H + hcol];
        const int nr0 = nt*16 + lhi*4;
        #pragma unroll
        for (int r=0;r<4;r++){
            const size_t p = (size_t)(nr0 + r)*H + hcol;
            const float gi = acc[0][r] + bb0;
            const float gf = acc[1][r] + bb1;
            const float gg = acc[2][r] + bb2;
            const float go = acc[3][r] + bb3;
            const float cn = sigmoidf_(gf)*cbuf[p] + sigmoidf_(gi)*tanhf(gg);
            const float hn = sigmoidf_(go)*tanhf(cn);
            cbuf[p] = cn;
            const u16 hb = f2bf_(hn);
            hohi[p] = hb;
            holo[p] = f2bf_(hn - bf2f_(hb));
            if (hof) hof[p] = hn;
        }
    }
}

// ================= old fallback kernels (unchanged logic) =================

__global__ __launch_bounds__(256)
void init_kernel(float* __restrict__ ws, const float* __restrict__ values){
    int i = blockIdx.x*256 + threadIdx.x;
    if (i >= WS_TOTAL) return;
    if (i < OFF_CTX) ws[i] = 0.0f;
    else ws[i] = values[(size_t)(TT-1)*NB*VS + (i - OFF_CTX)];
}

__global__ __launch_bounds__(256)
void conv_bf16_kernel(const float* __restrict__ src, u16* __restrict__ dst, int n4){
    int i = blockIdx.x*256 + threadIdx.x;
    if (i >= n4) return;
    float4 v = ((const float4*)src)[i];
    ushort4 o;
    o.x = f2bf_(v.x); o.y = f2bf_(v.y); o.z = f2bf_(v.z); o.w = f2bf_(v.w);
    ((ushort4*)dst)[i] = o;
}

template<int H, int KX, int KH, int MODE>
__global__ __launch_bounds__(256)
void lstm_kernel(const float* __restrict__ Wx, const float* __restrict__ Wh,
                 const float* __restrict__ bx, const float* __restrict__ bh,
                 const float* __restrict__ xbuf, const float* __restrict__ embW,
                 const int* __restrict__ text, int step,
                 const float* __restrict__ hread, float* __restrict__ hwrite,
                 float* __restrict__ cbuf)
{
    __shared__ __align__(16) float Xs[16][68];
    __shared__ __align__(16) float Ws[16][68];
    __shared__ float Gs[64][65];

    const int tid = threadIdx.x;
    const int h0  = blockIdx.x * 16;
    const int n0  = blockIdx.y * 64;

    const int sr = tid >> 2;
    const int sk = (tid & 3) << 2;
    const int wrow = (sr >> 4) * H + h0 + (sr & 15);
    const int n  = n0 + sr;

    const int tn4 = (tid & 15) * 4;
    const int tc4 = (tid >> 4) * 4;

    float acc[4][4];
    #pragma unroll
    for (int i=0;i<4;i++){
        #pragma unroll
        for (int j=0;j<4;j++) acc[i][j]=0.0f;
    }

    for (int k0 = 0; k0 < KX + KH; k0 += 16) {
        const int kb = k0 + sk;
        float4 xv, wv;
        if (k0 < KX) {
            if constexpr (MODE == 0) {
                if (kb < EMB) {
                    int idx = text[n * MAXLEN + step];
                    xv = *(const float4*)(embW + idx*EMB + kb);
                } else {
                    xv = *(const float4*)(xbuf + n*VS + (kb - EMB));
                }
            } else {
                xv = *(const float4*)(xbuf + n*KX + kb);
            }
            wv = *(const float4*)(Wx + wrow*KX + kb);
        } else {
            const int kh = kb - KX;
            xv = *(const float4*)(hread + n*KH + kh);
            wv = *(const float4*)(Wh + wrow*KH + kh);
        }
        Xs[sk+0][sr]=xv.x; Xs[sk+1][sr]=xv.y; Xs[sk+2][sr]=xv.z; Xs[sk+3][sr]=xv.w;
        Ws[sk+0][sr]=wv.x; Ws[sk+1][sr]=wv.y; Ws[sk+2][sr]=wv.z; Ws[sk+3][sr]=wv.w;
        __syncthreads();
        #pragma unroll
        for (int kk=0;kk<16;kk++){
            float4 xr = *(const float4*)&Xs[kk][tn4];
            float4 wr = *(const float4*)&Ws[kk][tc4];
            acc[0][0] += wr.x*xr.x; acc[0][1] += wr.x*xr.y; acc[0][2] += wr.x*xr.z; acc[0][3] += wr.x*xr.w;
            acc[1][0] += wr.y*xr.x; acc[1][1] += wr.y*xr.y; acc[1][2] += wr.y*xr.z; acc[1][3] += wr.y*xr.w;
            acc[2][0] += wr.z*xr.x; acc[2][1] += wr.z*xr.y; acc[2][2] += wr.z*xr.z; acc[2][3] += wr.z*xr.w;
            acc[3][0] += wr.w*xr.x; acc[3][1] += wr.w*xr.y; acc[3][2] += wr.w*xr.z; acc[3][3] += wr.w*xr.w;
        }
        __syncthreads();
    }

    #pragma unroll
    for (int ci=0; ci<4; ci++){
        const int c = tc4 + ci;
        const int row = (c >> 4) * H + h0 + (c & 15);
        const float b = bx[row] + bh[row];
        #pragma unroll
        for (int ni=0; ni<4; ni++) Gs[c][tn4+ni] = acc[ci][ni] + b;
    }
    __syncthreads();

    for (int p = tid; p < 16*64; p += 256){
        const int hl = p & 15, nl = p >> 4;
        const float gi = Gs[     hl][nl];
        const float gf = Gs[16 + hl][nl];
        const float gg = Gs[32 + hl][nl];
        const float go = Gs[48 + hl][nl];
        const int gn = n0 + nl, gh = h0 + hl;
        const float cold = cbuf[gn*H + gh];
        const float cn = sigmoidf_(gf)*cold + sigmoidf_(gi)*tanhf(gg);
        const float hn = sigmoidf_(go)*tanhf(cn);
        cbuf[gn*H + gh] = cn;
        hwrite[gn*H + gh] = hn;
    }
}

// ================= attention + prediction (shared) =================
// BF: values are bf16; CSPLIT: write ctx as bf16 hi/lo (new path) vs fp32 (old path).
template<int BF, int CSPLIT>
__global__ __launch_bounds__(512)
void attn_pred_kernel(const float* __restrict__ keys, const void* __restrict__ values_v,
                      const int* __restrict__ seqlen, const float* __restrict__ h3,
                      const float* __restrict__ linW, const float* __restrict__ linb,
                      const float* __restrict__ charW, const float* __restrict__ charb,
                      float* __restrict__ ctx, u16* __restrict__ ctx_hi, u16* __restrict__ ctx_lo,
                      float* __restrict__ out, int step)
{
    __shared__ float es[TT];
    __shared__ float redm[8], reds[8];
    __shared__ float cpart[8][128];
    __shared__ float cat[256];
    __shared__ float mid[128];

    const int tid  = threadIdx.x;
    const int n    = blockIdx.x;
    const int wave = tid >> 6, lane = tid & 63;

    const float2 hv = *(const float2*)(h3 + n*KS + lane*2);
    const int L = seqlen[n];

    for (int t0 = wave*4; t0 < TT; t0 += 32) {
        const float2* kp = (const float2*)(keys + ((size_t)t0*NB + n)*KS) + lane;
        const size_t rs = (size_t)NB*KS/2;
        float2 k0 = kp[0], k1 = kp[rs], k2 = kp[2*rs], k3 = kp[3*rs];
        float d0 = k0.x*hv.x + k0.y*hv.y;
        float d1 = k1.x*hv.x + k1.y*hv.y;
        float d2 = k2.x*hv.x + k2.y*hv.y;
        float d3 = k3.x*hv.x + k3.y*hv.y;
        #pragma unroll
        for (int off=32; off; off>>=1){
            d0 += __shfl_xor(d0, off, 64);
            d1 += __shfl_xor(d1, off, 64);
            d2 += __shfl_xor(d2, off, 64);
            d3 += __shfl_xor(d3, off, 64);
        }
        if (lane == 0){
            es[t0+0] = (t0+0 < L) ? d0 : -1e9f;
            es[t0+1] = (t0+1 < L) ? d1 : -1e9f;
            es[t0+2] = (t0+2 < L) ? d2 : -1e9f;
            es[t0+3] = (t0+3 < L) ? d3 : -1e9f;
        }
    }
    __syncthreads();

    float m = -3e38f;
    for (int t = tid; t < TT; t += 512) m = fmaxf(m, es[t]);
    #pragma unroll
    for (int off=32; off; off>>=1) m = fmaxf(m, __shfl_xor(m, off, 64));
    if (lane == 0) redm[wave] = m;
    __syncthreads();
    m = redm[0];
    #pragma unroll
    for (int w=1; w<8; ++w) m = fmaxf(m, redm[w]);

    float s = 0.0f;
    for (int t = tid; t < TT; t += 512) { float p = __expf(es[t]-m); es[t] = p; s += p; }
    #pragma unroll
    for (int off=32; off; off>>=1) s += __shfl_xor(s, off, 64);
    if (lane == 0) reds[wave] = s;
    __syncthreads();
    s = reds[0];
    #pragma unroll
    for (int w=1; w<8; ++w) s += reds[w];
    const float inv = 1.0f / s;

    float* attn_out = out + (size_t)NB*MAXLEN*VOCAB + ((size_t)step*NB + n)*TT;
    for (int t = tid; t < TT; t += 512) { float a = es[t]*inv; es[t] = a; attn_out[t] = a; }
    __syncthreads();

    float cax = 0.0f, cay = 0.0f;
    if constexpr (BF) {
        const u16* vals = (const u16*)values_v;
        #pragma unroll 4
        for (int j = 0; j < 125; ++j){
            const int t = wave + 8*j;
            const float a = es[t];
            const unsigned int v2 = *((const unsigned int*)(vals + ((size_t)t*NB + n)*VS) + lane);
            cax += a * __uint_as_float(v2 << 16);
            cay += a * __uint_as_float(v2 & 0xffff0000u);
        }
    } else {
        const float* vals = (const float*)values_v;
        #pragma unroll 4
        for (int j = 0; j < 125; ++j){
            const int t = wave + 8*j;
            const float a = es[t];
            const float2 v2 = *((const float2*)(vals + ((size_t)t*NB + n)*VS) + lane);
            cax += a * v2.x;
            cay += a * v2.y;
        }
    }
    cpart[wave][lane*2]   = cax;
    cpart[wave][lane*2+1] = cay;
    __syncthreads();

    if (tid < 128) {
        float cv = 0.0f;
        #pragma unroll
        for (int w=0; w<8; ++w) cv += cpart[w][tid];
        if constexpr (CSPLIT) {
            const u16 hb = f2bf_(cv);
            ctx_hi[n*VS + tid] = hb;
            ctx_lo[n*VS + tid] = f2bf_(cv - bf2f_(hb));
        } else {
            ctx[n*VS + tid] = cv;
        }
        cat[tid]        = h3[n*KS + tid];
        cat[128 + tid]  = cv;
    }
    __syncthreads();

    if (tid < 256) {
        const int o  = tid >> 1;
        const int kh = (tid & 1) * 128;
        const float* w = linW + o*(KS+VS) + kh;
        float a = 0.0f;
        #pragma unroll 8
        for (int k=0; k<128; ++k) a += w[k]*cat[kh+k];
        a += __shfl_xor(a, 1, 64);
        if (!(tid & 1)) mid[o] = a + linb[o];
    }
    __syncthreads();

    if (tid < VOCAB) {
        float a = charb[tid];
        const float* w = charW + tid*KS;
        #pragma unroll 8
        for (int k=0; k<KS; ++k) a += w[k]*mid[k];
        out[((size_t)n*MAXLEN + step)*VOCAB + tid] = a;
    }
}

// ================= host =================

extern "C" void kernel_launch(void* const* d_in, const int* in_sizes, int n_in,
                              void* d_out, int out_size, void* d_ws, size_t ws_size,
                              hipStream_t stream)
{
    const float* keys   = (const float*)d_in[0];
    const float* values = (const float*)d_in[1];
    const int*   seqlen = (const int*)  d_in[2];
    const int*   text   = (const int*)  d_in[3];
    const float* embW   = (const float*)d_in[4];
    const float* w_ih1  = (const float*)d_in[5];
    const float* w_hh1  = (const float*)d_in[6];
    const float* b_ih1  = (const float*)d_in[7];
    const float* b_hh1  = (const float*)d_in[8];
    const float* w_ih2  = (const float*)d_in[9];
    const float* w_hh2  = (const float*)d_in[10];
    const float* b_ih2  = (const float*)d_in[11];
    const float* b_hh2  = (const float*)d_in[12];
    const float* w_ih3  = (const float*)d_in[13];
    const float* w_hh3  = (const float*)d_in[14];
    const float* b_ih3  = (const float*)d_in[15];
    const float* b_hh3  = (const float*)d_in[16];
    const float* linW   = (const float*)d_in[17];
    const float* linb   = (const float*)d_in[18];
    const float* charW  = (const float*)d_in[19];
    const float* charb  = (const float*)d_in[20];
    float* out = (float*)d_out;
    float* ws  = (float*)d_ws;
    char*  wsb = (char*)d_ws;

    u16* vals_bf = (u16*)(wsb + STATE_BYTES);
    const int n4 = TT*NB*VS/4;

    if (ws_size >= FULL_BYTES) {
        // ---------- new MFMA split-bf16 path ----------
        u16* W1hi=(u16*)(wsb+OFF_W1HI); u16* W1lo=(u16*)(wsb+OFF_W1LO);
        u16* W2hi=(u16*)(wsb+OFF_W2HI); u16* W2lo=(u16*)(wsb+OFF_W2LO);
        u16* W3hi=(u16*)(wsb+OFF_W3HI); u16* W3lo=(u16*)(wsb+OFF_W3LO);
        u16* Ehi =(u16*)(wsb+OFF_EMBHI); u16* Elo =(u16*)(wsb+OFF_EMBLO);
        float* bs=(float*)(wsb+OFF_BSUM);
        u16* Chi =(u16*)(wsb+OFF_CTXHI); u16* Clo =(u16*)(wsb+OFF_CTXLO);
        u16* H1hi=(u16*)(wsb+OFF_H1HI);  u16* H1lo=(u16*)(wsb+OFF_H1LO);
        u16* H2hi=(u16*)(wsb+OFF_H2HI);  u16* H2lo=(u16*)(wsb+OFF_H2LO);
        u16* H3hi=(u16*)(wsb+OFF_H3HI);  u16* H3lo=(u16*)(wsb+OFF_H3LO);
        float* H3f=(float*)(wsb+OFF_H3F);
        float* C1=(float*)(wsb+OFF_C1);
        float* C2=(float*)(wsb+OFF_C2);
        float* C3=(float*)(wsb+OFF_C3);

        pack_w_kernel<<<(W1SZ+255)/256, 256, 0, stream>>>(w_ih1, w_hh1, W1hi, W1lo, EMB+VS, HID, W1SZ);
        pack_w_kernel<<<(W2SZ+255)/256, 256, 0, stream>>>(w_ih2, w_hh2, W2hi, W2lo, HID,    HID, W2SZ);
        pack_w_kernel<<<(W3SZ+255)/256, 256, 0, stream>>>(w_ih3, w_hh3, W3hi, W3lo, HID,    KS,  W3SZ);
        conv_bf16_kernel<<<(n4 + 255)/256, 256, 0, stream>>>(values, vals_bf, n4);
        prep_misc_kernel<<<1024, 256, 0, stream>>>(wsb, embW, b_ih1,b_hh1, b_ih2,b_hh2, b_ih3,b_hh3, values);

        constexpr int G12 = (HID/16)*(NB/16);   // 512 blocks, 4 waves each
        constexpr int G3  = (KS/16)*(NB/16);    // 128 blocks

        for (int t = 0; t < MAXLEN; ++t) {
            const int cur = t & 1, nxt = cur ^ 1;
            lstm_mfma4<HID, EMB+VS, HID, 0><<<G12, 256, 0, stream>>>(
                W1hi, W1lo, bs, Chi, Clo, Ehi, Elo, text, t,
                H1hi + cur*NH, H1lo + cur*NH,
                H1hi + nxt*NH, H1lo + nxt*NH, nullptr, C1);
            lstm_mfma4<HID, HID, HID, 1><<<G12, 256, 0, stream>>>(
                W2hi, W2lo, bs + BS1, H1hi + nxt*NH, H1lo + nxt*NH, nullptr, nullptr, nullptr, 0,
                H2hi + cur*NH, H2lo + cur*NH,
                H2hi + nxt*NH, H2lo + nxt*NH, nullptr, C2);
            lstm_mfma4<KS, HID, KS, 1><<<G3, 256, 0, stream>>>(
                W3hi, W3lo, bs + BS1 + BS2, H2hi + nxt*NH, H2lo + nxt*NH, nullptr, nullptr, nullptr, 0,
                H3hi + cur*NK, H3lo + cur*NK,
                H3hi + nxt*NK, H3lo + nxt*NK, H3f, C3);
            attn_pred_kernel<1,1><<<NB, 512, 0, stream>>>(
                keys, vals_bf, seqlen, H3f, linW, linb, charW, charb,
                nullptr, Chi, Clo, out, t);
        }
        return;
    }

    // ---------- old fallback path ----------
    float* h1  = ws;
    float* c1  = h1 + 2*NH;
    float* h2  = c1 + NH;
    float* c2  = h2 + 2*NH;
    float* h3  = c2 + NH;
    float* c3  = h3 + 2*NK;
    float* ctx = c3 + NK;

    const bool use_bf16 = (ws_size >= STATE_BYTES + VBF_BYTES);

    init_kernel<<<(WS_TOTAL + 255)/256, 256, 0, stream>>>(ws, values);
    if (use_bf16) {
        conv_bf16_kernel<<<(n4 + 255)/256, 256, 0, stream>>>(values, vals_bf, n4);
    }

    for (int t = 0; t < MAXLEN; ++t) {
        const int cur = t & 1, nxt = cur ^ 1;
        lstm_kernel<HID, EMB+VS, HID, 0><<<dim3(HID/16, NB/64), 256, 0, stream>>>(
            w_ih1, w_hh1, b_ih1, b_hh1, ctx, embW, text, t,
            h1 + cur*NH, h1 + nxt*NH, c1);
        lstm_kernel<HID, HID, HID, 1><<<dim3(HID/16, NB/64), 256, 0, stream>>>(
            w_ih2, w_hh2, b_ih2, b_hh2, h1 + nxt*NH, nullptr, nullptr, t,
            h2 + cur*NH, h2 + nxt*NH, c2);
        lstm_kernel<KS, HID, KS, 1><<<dim3(KS/16, NB/64), 256, 0, stream>>>(
            w_ih3, w_hh3, b_ih3, b_hh3, h2 + nxt*NH, nullptr, nullptr, t,
            h3 + cur*NK, h3 + nxt*NK, c3);
        if (use_bf16)
            attn_pred_kernel<1,0><<<NB, 512, 0, stream>>>(
                keys, vals_bf, seqlen, h3 + nxt*NK,
                linW, linb, charW, charb, ctx, nullptr, nullptr, out, t);
        else
            attn_pred_kernel<0,0><<<NB, 512, 0, stream>>>(
                keys, values, seqlen, h3 + nxt*NK,
                linW, linb, charW, charb, ctx, nullptr, nullptr, out, t);
    }
}